// Round 1
// baseline (454.617 us; speedup 1.0000x reference)
//
#include <hip/hip_runtime.h>
#include <math.h>
#include <stdint.h>

#define DEV static __device__ __forceinline__

constexpr int D  = 256;
constexpr int S  = 4096;
constexpr int B  = 4;
constexpr int BQ = 64;          // query rows per block (4 waves x 16)
constexpr int BK = 64;          // keys per iteration
constexpr int KSTR = D + 8;     // 264: +8 bf16 pad -> row stride 528B == 4 banks mod 32
constexpr int VSTR = BK + 8;    // 72:  144B == 4 banks mod 32
constexpr int PSTR = BK + 8;

typedef short  bf16x8 __attribute__((ext_vector_type(8)));
typedef float  f32x4  __attribute__((ext_vector_type(4)));

DEV unsigned short f2bf(float f) {   // RNE float -> bf16 bits
  unsigned int u = __float_as_uint(f);
  return (unsigned short)((u + 0x7fffu + ((u >> 16) & 1u)) >> 16);
}
DEV float bf2f(unsigned short h) {
  return __uint_as_float(((unsigned int)h) << 16);
}
DEV f32x4 zero4() { f32x4 z = {0.f, 0.f, 0.f, 0.f}; return z; }

// ---------------- projection: Q = (xWq^T + bq)/16, K = xWk^T + bk, V^T = (xWv^T + bv)^T ----
constexpr int PROWS = 16;

DEV void proj_rows(const float* __restrict__ xblk, const float* __restrict__ Wrow,
                   float bias, float scale, float* acc) {
  #pragma unroll
  for (int r = 0; r < PROWS; ++r) acc[r] = 0.f;
  #pragma unroll 2
  for (int k = 0; k < D; k += 4) {
    float4 w = *(const float4*)(Wrow + k);
    #pragma unroll
    for (int r = 0; r < PROWS; ++r) {
      const float* xr = xblk + r * D + k;   // workgroup-uniform -> scalar loads
      float a = acc[r];
      a = fmaf(xr[0], w.x, a);
      a = fmaf(xr[1], w.y, a);
      a = fmaf(xr[2], w.z, a);
      a = fmaf(xr[3], w.w, a);
      acc[r] = a;
    }
  }
  #pragma unroll
  for (int r = 0; r < PROWS; ++r) acc[r] = (acc[r] + bias) * scale;
}

__global__ __launch_bounds__(256) void msp_proj(
    const float* __restrict__ x,
    const float* __restrict__ Wq, const float* __restrict__ bq,
    const float* __restrict__ Wk, const float* __restrict__ bk,
    const float* __restrict__ Wv, const float* __restrict__ bv,
    unsigned short* __restrict__ Qb, unsigned short* __restrict__ Kb,
    unsigned short* __restrict__ Vt)
{
  const int e    = threadIdx.x;           // output column 0..255
  const int row0 = blockIdx.x * PROWS;    // global row over B*S
  const int b    = row0 / S;
  const int s0   = row0 % S;
  const float* xblk = x + (size_t)row0 * D;
  float acc[PROWS];

  // Q (1/sqrt(d)=1/16 folded in; exact pow2 scale => single rounding)
  proj_rows(xblk, Wq + (size_t)e * D, bq[e], 0.0625f, acc);
  #pragma unroll
  for (int r = 0; r < PROWS; ++r)
    Qb[(size_t)(row0 + r) * D + e] = f2bf(acc[r]);

  // K
  proj_rows(xblk, Wk + (size_t)e * D, bk[e], 1.f, acc);
  #pragma unroll
  for (int r = 0; r < PROWS; ++r)
    Kb[(size_t)(row0 + r) * D + e] = f2bf(acc[r]);

  // V, stored transposed [b][e][s] so PV B-fragments are contiguous in t
  proj_rows(xblk, Wv + (size_t)e * D, bv[e], 1.f, acc);
  unsigned short tmp[PROWS];
  #pragma unroll
  for (int r = 0; r < PROWS; ++r) tmp[r] = f2bf(acc[r]);
  size_t vbase = ((size_t)b * D + e) * S + s0;   // 16 contiguous bf16 => two 16B stores
  *(uint4*)&Vt[vbase]     = *(const uint4*)&tmp[0];
  *(uint4*)&Vt[vbase + 8] = *(const uint4*)&tmp[8];
}

// ---------------- flash attention with periodic bias ----------------
__global__ __launch_bounds__(256) void msp_attn(
    const unsigned short* __restrict__ Qb,
    const unsigned short* __restrict__ Kb,
    const unsigned short* __restrict__ Vtg,   // [b][e][s]
    const float* __restrict__ beta,
    float* __restrict__ out)
{
  __shared__ unsigned short Kt[BK][KSTR];
  __shared__ unsigned short Vs[D][VSTR];
  __shared__ unsigned short Pt[4][16][PSTR];
  __shared__ float biasTab[720];

  const int tid  = threadIdx.x;
  const int wave = tid >> 6;
  const int lane = tid & 63;
  const int l15  = lane & 15;
  const int quad = lane >> 4;

  const int b  = blockIdx.y;
  const int q0 = blockIdx.x * BQ;
  const int qw = q0 + wave * 16;            // wave's first query row (batch-local)

  // bias table: bias(d) for d = (i-j) mod 720 (720 = lcm(24,720))
  {
    float b0 = beta[0], b1 = beta[1];
    for (int i = tid; i < 720; i += 256) {
      float d = (float)i;
      biasTab[i] = b0 * cosf(d * 0.26179938779914944f)     // 2*pi/24
                 + b1 * cosf(d * 0.008726646259971648f);   // 2*pi/720
    }
  }

  // Q fragments: A[m=lane&15][k=quad*8+j], 8 k-fragments of 32
  bf16x8 qf[8];
  {
    const unsigned short* qp = Qb + ((size_t)(b * S) + qw + l15) * D + quad * 8;
    #pragma unroll
    for (int kf = 0; kf < 8; ++kf)
      qf[kf] = *(const bf16x8*)(qp + kf * 32);
  }

  float m_run[4], l_run[4];
  #pragma unroll
  for (int r = 0; r < 4; ++r) { m_run[r] = -INFINITY; l_run[r] = 0.f; }

  f32x4 oacc[16];
  #pragma unroll
  for (int et = 0; et < 16; ++et) oacc[et] = zero4();

  int arow[4];
  #pragma unroll
  for (int r = 0; r < 4; ++r) arow[r] = (qw + quad * 4 + r) % 720;

  const unsigned short* kgb = Kb  + (size_t)(b * S) * D;
  const unsigned short* vgb = Vtg + (size_t)(b * D) * S;

  __syncthreads();   // biasTab ready

  int tmod = 0;      // t0 mod 720
  for (int t0 = 0; t0 < S; t0 += BK) {
    __syncthreads(); // previous iteration's LDS reads drained

    { // stage K tile [64][256] and V^T tile [256][64]
      const unsigned short* kg = kgb + (size_t)t0 * D;
      #pragma unroll
      for (int c = 0; c < 8; ++c) {
        int lin = tid + c * 256;
        int row = lin >> 5;
        int col = (lin & 31) << 3;
        *(uint4*)&Kt[row][col] = *(const uint4*)(kg + row * D + col);
      }
      const unsigned short* vg = vgb + t0;
      #pragma unroll
      for (int c = 0; c < 8; ++c) {
        int lin = tid + c * 256;
        int row = lin >> 3;
        int col = (lin & 7) << 3;
        *(uint4*)&Vs[row][col] = *(const uint4*)(vg + (size_t)row * S + col);
      }
    }
    __syncthreads();

    // S = Q K^T  (scale pre-folded into Q)
    f32x4 sc[4];
    #pragma unroll
    for (int nt = 0; nt < 4; ++nt) sc[nt] = zero4();
    #pragma unroll
    for (int kf = 0; kf < 8; ++kf) {
      #pragma unroll
      for (int nt = 0; nt < 4; ++nt) {
        bf16x8 bk8 = *(const bf16x8*)&Kt[nt * 16 + l15][kf * 32 + quad * 8];
        sc[nt] = __builtin_amdgcn_mfma_f32_16x16x32_bf16(qf[kf], bk8, sc[nt], 0, 0, 0);
      }
    }

    // + periodic bias
    #pragma unroll
    for (int nt = 0; nt < 4; ++nt) {
      int jo = tmod + nt * 16 + l15;
      #pragma unroll
      for (int r = 0; r < 4; ++r) {
        int idx = arow[r] - jo;               // in (-783, 720)
        idx += (idx < 0) ? 720 : 0;
        idx += (idx < 0) ? 720 : 0;
        sc[nt][r] += biasTab[idx];
      }
    }

    // online softmax: row stats live per (quad, reg), replicated over 16 lanes
    float tmax[4];
    #pragma unroll
    for (int r = 0; r < 4; ++r)
      tmax[r] = fmaxf(fmaxf(sc[0][r], sc[1][r]), fmaxf(sc[2][r], sc[3][r]));
    #pragma unroll
    for (int off = 1; off < 16; off <<= 1) {
      #pragma unroll
      for (int r = 0; r < 4; ++r)
        tmax[r] = fmaxf(tmax[r], __shfl_xor(tmax[r], off, 64));
    }
    float alpha[4];
    #pragma unroll
    for (int r = 0; r < 4; ++r) {
      float mn = fmaxf(m_run[r], tmax[r]);
      alpha[r] = __expf(m_run[r] - mn);       // exp(-inf)=0 on first tile
      m_run[r] = mn;
    }

    // p = exp(s - m); sum the bf16-ROUNDED p so normalization cancels rounding
    float ps[4] = {0.f, 0.f, 0.f, 0.f};
    #pragma unroll
    for (int nt = 0; nt < 4; ++nt) {
      #pragma unroll
      for (int r = 0; r < 4; ++r) {
        float p = __expf(sc[nt][r] - m_run[r]);
        unsigned short hp = f2bf(p);
        Pt[wave][quad * 4 + r][nt * 16 + l15] = hp;
        ps[r] += bf2f(hp);
      }
    }
    #pragma unroll
    for (int off = 1; off < 16; off <<= 1) {
      #pragma unroll
      for (int r = 0; r < 4; ++r)
        ps[r] += __shfl_xor(ps[r], off, 64);
    }
    #pragma unroll
    for (int r = 0; r < 4; ++r) l_run[r] = l_run[r] * alpha[r] + ps[r];

    // rescale O accumulator (same row mapping as C layout => alpha[reg] applies directly)
    #pragma unroll
    for (int et = 0; et < 16; ++et) {
      #pragma unroll
      for (int r = 0; r < 4; ++r) oacc[et][r] *= alpha[r];
    }

    __syncthreads();  // Pt visible across lanes (and Vs reads ordered)

    // O += P V : A = P from LDS in A-layout, B = V^T tile (contiguous in t)
    bf16x8 a0 = *(const bf16x8*)&Pt[wave][l15][quad * 8];
    bf16x8 a1 = *(const bf16x8*)&Pt[wave][l15][32 + quad * 8];
    #pragma unroll
    for (int et = 0; et < 16; ++et) {
      bf16x8 v0 = *(const bf16x8*)&Vs[et * 16 + l15][quad * 8];
      bf16x8 v1 = *(const bf16x8*)&Vs[et * 16 + l15][32 + quad * 8];
      oacc[et] = __builtin_amdgcn_mfma_f32_16x16x32_bf16(a0, v0, oacc[et], 0, 0, 0);
      oacc[et] = __builtin_amdgcn_mfma_f32_16x16x32_bf16(a1, v1, oacc[et], 0, 0, 0);
    }

    tmod += BK;
    if (tmod >= 720) tmod -= 720;
  }

  // epilogue: normalize and store fp32
  float inv[4];
  #pragma unroll
  for (int r = 0; r < 4; ++r) inv[r] = 1.f / l_run[r];

  float* ob = out + ((size_t)(b * S) + qw) * D;
  #pragma unroll
  for (int et = 0; et < 16; ++et) {
    #pragma unroll
    for (int r = 0; r < 4; ++r)
      ob[(size_t)(quad * 4 + r) * D + et * 16 + l15] = oacc[et][r] * inv[r];
  }
}

extern "C" void kernel_launch(void* const* d_in, const int* in_sizes, int n_in,
                              void* d_out, int out_size, void* d_ws, size_t ws_size,
                              hipStream_t stream) {
  const float* x    = (const float*)d_in[0];
  const float* Wq   = (const float*)d_in[1];
  const float* bq   = (const float*)d_in[2];
  const float* Wk   = (const float*)d_in[3];
  const float* bk   = (const float*)d_in[4];
  const float* Wv   = (const float*)d_in[5];
  const float* bv   = (const float*)d_in[6];
  const float* beta = (const float*)d_in[7];
  float* out = (float*)d_out;

  // workspace: Q | K | V^T, bf16, 8 MB each (24 MB total)
  unsigned short* Qb = (unsigned short*)d_ws;
  unsigned short* Kb = Qb + (size_t)B * S * D;
  unsigned short* Vt = Kb + (size_t)B * S * D;

  msp_proj<<<(B * S) / PROWS, 256, 0, stream>>>(x, Wq, bq, Wk, bk, Wv, bv, Qb, Kb, Vt);
  msp_attn<<<dim3(S / BQ, B), 256, 0, stream>>>(Qb, Kb, Vt, beta, out);
}